// Round 8
// baseline (4549.632 us; speedup 1.0000x reference)
//
#include <hip/hip_runtime.h>
#include <math.h>

#define BATCH 16
#define T 512
#define NT 6
#define START 4
#define STOP 5
#define NEGV -10000.0f
#define LOG2E 1.4426950408889634f
#define NBLK 16  // lstm blocks; block k owns gate cols {n*256 + k*16 + c}

typedef __attribute__((ext_vector_type(8))) short short8;
typedef __attribute__((ext_vector_type(4))) float f32x4;
typedef __attribute__((ext_vector_type(4))) int i32x4;

__device__ __forceinline__ float fast_sig(float x) {
    float e = __builtin_amdgcn_exp2f(-LOG2E * x);
    return __builtin_amdgcn_rcpf(1.f + e);
}
__device__ __forceinline__ float fast_tanh(float x) {
    float e = __builtin_amdgcn_exp2f(-2.f * LOG2E * x);
    return (1.f - e) * __builtin_amdgcn_rcpf(1.f + e);
}
__device__ __forceinline__ unsigned bf16_rne(float f) {
    unsigned u = __builtin_bit_cast(unsigned, f);
    u += 0x7FFFu + ((u >> 16) & 1u);
    return u >> 16;
}
// LDS-only barrier: does NOT drain vmcnt -> prefetches/publishes stay in flight.
__device__ __forceinline__ void bar_lds() {
    asm volatile("s_waitcnt lgkmcnt(0)" ::: "memory");
    __builtin_amdgcn_sched_barrier(0);
    __builtin_amdgcn_s_barrier();
}

// ws layout (float units):
//   [0, 8388608)        Xp2 fp32 [t][k][n][lane][j]  (32 MB)
//                       Hg u64[512][2][8][128] ALIASES first 8MB: unit = {2 bf16 h | tag<<32},
//                       tag = t+1 (1..512). Writes for step t end at (2t+2)*8KB <= Xp2 offset
//                       64KB*t already consumed; fp32 bit patterns (and 0xAA poison) never
//                       equal a valid tag; input_proj rewrites the whole region each replay.
//   [8388608, 8650752)  WihT fp32 (dead after input_proj)
//   [8650752, 8781824)  Wf bf16 MFMA B-fragments (512 KB)
//   [8781824, 8830976)  feats fp32 [b][t][6]

__global__ void transpose_wih(const float* __restrict__ W_ih, float* __restrict__ WihT) {
    int o = blockIdx.x * blockDim.x + threadIdx.x;
    if (o >= 256 * 1024) return;
    int k = o >> 10;
    int g = o & 1023;
    WihT[o] = W_ih[g * 256 + k];
}

// Pack W_hh (fp32 [1024][256]) into bf16 MFMA B-fragments.
__global__ void wf_prep(const float* __restrict__ W_hh, unsigned short* __restrict__ Wf) {
    int t = blockIdx.x * 256 + threadIdx.x;  // 0..32767
    int l = t & 63, kt = (t >> 6) & 7, n = (t >> 9) & 3, w = t >> 11;
    int g = n * 256 + w * 16 + (l & 15);
    int kk = kt * 32 + (l >> 4) * 8;
    const float* src = W_hh + g * 256 + kk;
    unsigned short* dst = Wf + (size_t)t * 8;
#pragma unroll
    for (int j = 0; j < 8; j++) dst[j] = (unsigned short)bf16_rne(src[j]);
}

// One block = 16 (b,t) rows, 1024 threads = 1 per gate. Writes Xp2 in MFMA C-layout.
__global__ __launch_bounds__(1024) void input_proj(const int* __restrict__ sentence,
                                                   const float* __restrict__ embedding,
                                                   const float* __restrict__ WihT,
                                                   const float* __restrict__ b_ih,
                                                   const float* __restrict__ b_hh,
                                                   float* __restrict__ Xp2) {
    __shared__ __align__(16) float emb[16][260];
    int tid = threadIdx.x;
    int bt0 = blockIdx.x * 16;
    {
        int r = tid >> 6, j = tid & 63;
        int row = sentence[bt0 + r];
        const float4* src = (const float4*)(embedding + (size_t)row * 256);
        float4 v = src[j];
        float* dst = &emb[r][j * 4];
        dst[0] = v.x; dst[1] = v.y; dst[2] = v.z; dst[3] = v.w;
    }
    __syncthreads();
    int g = tid;
    float bias = b_ih[g] + b_hh[g];
    float acc[16];
#pragma unroll
    for (int r = 0; r < 16; r++) acc[r] = bias;
    const float* wp = WihT + g;
    for (int k4 = 0; k4 < 64; k4++) {
        float w0 = wp[(k4 * 4 + 0) * 1024];
        float w1 = wp[(k4 * 4 + 1) * 1024];
        float w2 = wp[(k4 * 4 + 2) * 1024];
        float w3 = wp[(k4 * 4 + 3) * 1024];
#pragma unroll
        for (int r = 0; r < 16; r++) {
            float4 e = *(const float4*)&emb[r][k4 * 4];
            acc[r] += w0 * e.x + w1 * e.y + w2 * e.z + w3 * e.w;
        }
    }
    int b = bt0 >> 9, t0 = bt0 & 511;
    int q = b >> 2, j = b & 3;
    int n = g >> 8, u = g & 255, k = u >> 4, cc = u & 15;
    int lane = q * 16 + cc;
#pragma unroll
    for (int r = 0; r < 16; r++) {
        int t = t0 + r;
        Xp2[(size_t)(((t * 16 + k) * 4 + n) * 64 + lane) * 4 + j] = acc[r];
    }
}

// Issue the 32 gather loads (latency overlapped by caller's subsequent VALU work).
#define GISSUE(vv, base)                                                                      \
    {                                                                                         \
        const unsigned long long* hp_ = (base);                                               \
        _Pragma("unroll") for (int kt = 0; kt < 8; kt++)                                      \
            _Pragma("unroll") for (int e = 0; e < 4; e++)                                     \
                vv[kt][e] = __hip_atomic_load(hp_ + kt * 16 + e, __ATOMIC_RELAXED,            \
                                              __HIP_MEMORY_SCOPE_AGENT);                      \
        __builtin_amdgcn_sched_barrier(0);                                                    \
    }

// Validate tags; on (rare) miss: backoff + reload. Then pack payloads into af.
#define GVALID(af, vv, base, tagw)                                                            \
    {                                                                                         \
        const unsigned long long* hp_ = (base);                                               \
        while (true) {                                                                        \
            bool ok_ = true;                                                                  \
            _Pragma("unroll") for (int kt = 0; kt < 8; kt++)                                  \
                _Pragma("unroll") for (int e = 0; e < 4; e++)                                 \
                    ok_ = ok_ & ((unsigned)(vv[kt][e] >> 32) == (unsigned)(tagw));            \
            if (__all(ok_)) break;                                                            \
            asm volatile("s_sleep 2");                                                        \
            _Pragma("unroll") for (int kt = 0; kt < 8; kt++)                                  \
                _Pragma("unroll") for (int e = 0; e < 4; e++)                                 \
                    vv[kt][e] = __hip_atomic_load(hp_ + kt * 16 + e, __ATOMIC_RELAXED,        \
                                                  __HIP_MEMORY_SCOPE_AGENT);                  \
        }                                                                                     \
        _Pragma("unroll") for (int kt = 0; kt < 8; kt++) {                                    \
            i32x4 pk_ = {(int)vv[kt][0], (int)vv[kt][1], (int)vv[kt][2], (int)vv[kt][3]};     \
            af[kt] = __builtin_bit_cast(short8, pk_);                                         \
        }                                                                                     \
    }

#define ACT_PUB(gl, c0, c1, dstbase)                                                          \
    {                                                                                         \
        float iv0 = fast_sig(gl[0][b_own][ul0]), iv1 = fast_sig(gl[0][b_own][ul0 + 1]);       \
        float fg0 = fast_sig(gl[1][b_own][ul0]), fg1 = fast_sig(gl[1][b_own][ul0 + 1]);       \
        float gv0 = fast_tanh(gl[2][b_own][ul0]), gv1 = fast_tanh(gl[2][b_own][ul0 + 1]);     \
        float ov0 = fast_sig(gl[3][b_own][ul0]), ov1 = fast_sig(gl[3][b_own][ul0 + 1]);       \
        c0 = fg0 * c0 + iv0 * gv0;                                                            \
        c1 = fg1 * c1 + iv1 * gv1;                                                            \
        unsigned h0 = bf16_rne(ov0 * fast_tanh(c0));                                          \
        unsigned h1 = bf16_rne(ov1 * fast_tanh(c1));                                          \
        unsigned long long unit = (unsigned long long)(h0 | (h1 << 16)) |                     \
                                  ((unsigned long long)(unsigned)(t + 1) << 32);              \
        __hip_atomic_store((dstbase) + wunit, unit, __ATOMIC_RELAXED,                         \
                           __HIP_MEMORY_SCOPE_AGENT);                                         \
    }

// 16 blocks x 256 threads; weights register-resident (32 VGPR). Two phase-offset batch
// groups (0-7, 8-15). Self-validating {h,h,tag} u64 exchange (1 LLC RTT, no flags/drains);
// gathers issued >= 1 RTT before validation so first-try success is the norm; s_sleep
// backoff prevents retry storms (round-7 failure mode).
__global__ __launch_bounds__(256, 1) void lstm_mfma(const unsigned short* __restrict__ Wf,
                                                    const float* Xp2,
                                                    unsigned long long* Hg) {
    __shared__ float glA[4][8][16];
    __shared__ float glB[4][8][16];
    int tid = threadIdx.x;
    int k = blockIdx.x;
    int n = tid >> 6;  // wave = gate type
    int l = tid & 63;
    int q = l >> 4;

    short8 wr[8];
#pragma unroll
    for (int kt = 0; kt < 8; kt++)
        wr[kt] = *(const short8*)(Wf + ((size_t)((k * 4 + n) * 8 + kt) * 64 + l) * 8);

    const char* xbase = (const char*)Xp2 + ((size_t)k * 4 + n) * 1024 + (size_t)l * 16;
    f32x4 xv = *(const f32x4*)xbase;

    // A-frag u64 base: row r=l&7 (dup for rows 8-15), unit p = kt*16 + q*4 + e
    int abase = (l & 7) * 128 + q * 4;
    // writer (tid<64): b_own=tid>>3, cols ul0,ul0+1; unit index within step-group page
    int b_own = tid >> 3, ul0 = (tid & 7) * 2;
    int wunit = b_own * 128 + k * 8 + (tid & 7);

    float cA0 = 0.f, cA1 = 0.f, cB0 = 0.f, cB1 = 0.f;
    unsigned long long vA[8][4], vB[8][4];
    short8 afA[8], afB[8];

    for (int t = 0; t < T; t++) {
        f32x4 xnext = xv;
        if (t + 1 < T) xnext = *(const f32x4*)(xbase + (size_t)(t + 1) * 65536);

        // ---- P1: group A. afA loads were issued at the end of the previous iteration ----
        f32x4 acc = xv;
        if (t > 0) {
            GVALID(afA, vA, Hg + (size_t)((t - 1) * 2 + 0) * 1024 + abase, (unsigned)t)
#pragma unroll
            for (int kt = 0; kt < 8; kt++)
                acc = __builtin_amdgcn_mfma_f32_16x16x32_bf16(afA[kt], wr[kt], acc, 0, 0, 0);
        }
        if (q < 2) {
            int c = l & 15;
#pragma unroll
            for (int j = 0; j < 4; j++) glA[n][q * 4 + j][c] = acc[j];
        }
        bar_lds();  // glA ready (LDS-only; global ops stay in flight)
        if (t > 0) GISSUE(vB, Hg + (size_t)((t - 1) * 2 + 1) * 1024 + abase)  // h_B(t-1)
        if (tid < 64) ACT_PUB(glA, cA0, cA1, Hg + (size_t)(t * 2 + 0) * 1024)  // overlaps vB

        // ---- P2: group B ----
        acc = xv;
        if (t > 0) {
            GVALID(afB, vB, Hg + (size_t)((t - 1) * 2 + 1) * 1024 + abase, (unsigned)t)
#pragma unroll
            for (int kt = 0; kt < 8; kt++)
                acc = __builtin_amdgcn_mfma_f32_16x16x32_bf16(afB[kt], wr[kt], acc, 0, 0, 0);
        }
        if (q >= 2) {
            int c = l & 15;
#pragma unroll
            for (int j = 0; j < 4; j++) glB[n][q * 4 + j - 8][c] = acc[j];
        }
        bar_lds();  // glB ready
        if (t + 1 < T) GISSUE(vA, Hg + (size_t)(t * 2 + 0) * 1024 + abase)  // h_A(t), tag t+1
        if (tid < 64) ACT_PUB(glB, cB0, cB1, Hg + (size_t)(t * 2 + 1) * 1024)

        xv = xnext;
    }
}

// feats[b][t][tag] = h(b,t) . W_out[tag] + b_out[tag].  2048 blocks x 256, wave = one (b,t).
__global__ __launch_bounds__(256) void feats_k(const unsigned long long* __restrict__ Hg,
                                               const float* __restrict__ W_out,
                                               const float* __restrict__ b_out,
                                               float* __restrict__ feats) {
    int wid = blockIdx.x * 4 + (threadIdx.x >> 6);
    int l = threadIdx.x & 63;
    int b = wid >> 9, t = wid & 511;
    int g = b >> 3, bg = b & 7;
    // lane l covers u = l*4 + {0..3} -> units p = 2l, 2l+1 -> one 16B load
    const uint4* src = (const uint4*)(Hg + ((size_t)(t * 2 + g) * 8 + bg) * 128) + l;
    uint4 v = *src;
    float h0 = __builtin_bit_cast(float, (v.x & 0xffffu) << 16);
    float h1 = __builtin_bit_cast(float, v.x & 0xffff0000u);
    float h2 = __builtin_bit_cast(float, (v.z & 0xffffu) << 16);
    float h3 = __builtin_bit_cast(float, v.z & 0xffff0000u);
    int ub = l * 4;
#pragma unroll
    for (int tag = 0; tag < 6; tag++) {
        float4 w = *(const float4*)(W_out + tag * 256 + ub);
        float p = h0 * w.x + h1 * w.y + h2 * w.z + h3 * w.w;
#pragma unroll
        for (int off = 32; off; off >>= 1) p += __shfl_down(p, off);
        if (l == 0) feats[((size_t)b * 512 + t) * 6 + tag] = p + b_out[tag];
    }
}

// 16 blocks x 64 threads. Lane nx owns next-tag nx; fv broadcast via shfl each step.
__global__ __launch_bounds__(64) void crf_scan(const float* __restrict__ feats,
                                               const float* __restrict__ trans,
                                               float* __restrict__ out) {
    __shared__ float fl[T * 6];
    __shared__ unsigned char bp[T * 8];
    int b = blockIdx.x, tid = threadIdx.x;
    const float4* src = (const float4*)(feats + (size_t)b * 3072);
#pragma unroll
    for (int i = 0; i < 12; i++) ((float4*)fl)[tid + i * 64] = src[tid + i * 64];
    int nx = (tid < 6) ? tid : 0;
    float tr0 = trans[nx * 6 + 0], tr1 = trans[nx * 6 + 1], tr2 = trans[nx * 6 + 2],
          tr3 = trans[nx * 6 + 3], tr4 = trans[nx * 6 + 4], tr5 = trans[nx * 6 + 5];
    float fv0 = NEGV, fv1 = NEGV, fv2 = NEGV, fv3 = NEGV, fv4 = 0.f, fv5 = NEGV;  // START=4
    __syncthreads();
    for (int t = 0; t < T; t++) {
        float best = fv0 + tr0; int arg = 0; float s;
        s = fv1 + tr1; if (s > best) { best = s; arg = 1; }
        s = fv2 + tr2; if (s > best) { best = s; arg = 2; }
        s = fv3 + tr3; if (s > best) { best = s; arg = 3; }
        s = fv4 + tr4; if (s > best) { best = s; arg = 4; }
        s = fv5 + tr5; if (s > best) { best = s; arg = 5; }  // strict >: first-max
        float nf = best + fl[t * 6 + nx];
        if (tid < 6) bp[t * 8 + tid] = (unsigned char)arg;
        fv0 = __shfl(nf, 0); fv1 = __shfl(nf, 1); fv2 = __shfl(nf, 2);
        fv3 = __shfl(nf, 3); fv4 = __shfl(nf, 4); fv5 = __shfl(nf, 5);
    }
    __syncthreads();
    if (tid == 0) {
        float best = fv0 + trans[STOP * 6 + 0]; int arg = 0; float s;
        s = fv1 + trans[STOP * 6 + 1]; if (s > best) { best = s; arg = 1; }
        s = fv2 + trans[STOP * 6 + 2]; if (s > best) { best = s; arg = 2; }
        s = fv3 + trans[STOP * 6 + 3]; if (s > best) { best = s; arg = 3; }
        s = fv4 + trans[STOP * 6 + 4]; if (s > best) { best = s; arg = 4; }
        s = fv5 + trans[STOP * 6 + 5]; if (s > best) { best = s; arg = 5; }
        out[b] = best;
        int tag = arg;
        float* paths = out + 16 + (size_t)b * 512;
        for (int t = T - 1; t >= 0; t--) {
            paths[t] = (float)tag;
            tag = bp[t * 8 + tag];
        }
    }
}

extern "C" void kernel_launch(void* const* d_in, const int* in_sizes, int n_in,
                              void* d_out, int out_size, void* d_ws, size_t ws_size,
                              hipStream_t stream) {
    const int* sentence = (const int*)d_in[0];
    const float* embedding = (const float*)d_in[1];
    const float* W_ih = (const float*)d_in[2];
    const float* W_hh = (const float*)d_in[3];
    const float* b_ih = (const float*)d_in[4];
    const float* b_hh = (const float*)d_in[5];
    const float* W_out = (const float*)d_in[6];
    const float* b_out = (const float*)d_in[7];
    const float* trans = (const float*)d_in[8];
    float* out = (float*)d_out;
    float* ws = (float*)d_ws;

    float* Xp2 = ws;
    unsigned long long* Hg = (unsigned long long*)ws;  // aliases Xp2 head (consumed region)
    float* WihT = ws + 8388608;
    unsigned short* Wf = (unsigned short*)(ws + 8650752);
    float* feats = ws + 8781824;

    hipLaunchKernelGGL(transpose_wih, dim3(1024), dim3(256), 0, stream, W_ih, WihT);
    hipLaunchKernelGGL(input_proj, dim3(BATCH * T / 16), dim3(1024), 0, stream,
                       sentence, embedding, WihT, b_ih, b_hh, Xp2);
    hipLaunchKernelGGL(wf_prep, dim3(128), dim3(256), 0, stream, W_hh, Wf);
    hipLaunchKernelGGL(lstm_mfma, dim3(NBLK), dim3(256), 0, stream, Wf, Xp2, Hg);
    hipLaunchKernelGGL(feats_k, dim3(2048), dim3(256), 0, stream, Hg, W_out, b_out, feats);
    hipLaunchKernelGGL(crf_scan, dim3(BATCH), dim3(64), 0, stream, feats, trans, out);
}

// Round 9
// 1619.323 us; speedup vs baseline: 2.8096x; 2.8096x over previous
//
#include <hip/hip_runtime.h>
#include <math.h>

#define BATCH 16
#define T 512
#define NT 6
#define START 4
#define STOP 5
#define NEGV -10000.0f
#define LOG2E 1.4426950408889634f
#define NBLK 16  // lstm blocks; block k owns h-units k*16..k*16+15 (gate cols n*256+k*16+c)

typedef __attribute__((ext_vector_type(8))) short short8;
typedef __attribute__((ext_vector_type(4))) float f32x4;
typedef __attribute__((ext_vector_type(4))) int i32x4;

__device__ __forceinline__ float fast_sig(float x) {
    float e = __builtin_amdgcn_exp2f(-LOG2E * x);
    return __builtin_amdgcn_rcpf(1.f + e);
}
__device__ __forceinline__ float fast_tanh(float x) {
    float e = __builtin_amdgcn_exp2f(-2.f * LOG2E * x);
    return (1.f - e) * __builtin_amdgcn_rcpf(1.f + e);
}
__device__ __forceinline__ unsigned bf16_rne(float f) {
    unsigned u = __builtin_bit_cast(unsigned, f);
    u += 0x7FFFu + ((u >> 16) & 1u);
    return u >> 16;
}

// ws layout (float units):
//   [0, 8388608)        Xp2 fp32 [t][k][n][lane][j]  (32 MB)
//                       Hg u64[512][2048] ALIASES first 8MB: unit = {2 bf16 h | tag<<32},
//                       tag = t+1 (1..512). h-writes for step t at 16KB*t trail Xp2 reads
//                       at 64KB*t by 4x -> no clobber. fp32 bit patterns / 0xAA poison never
//                       equal a valid tag; gathers are agent-scope atomics (LLC-direct) so
//                       XCD-L2 staleness cannot fake a tag.
//   [8388608, 8650752)  WihT fp32 (dead after input_proj; Xp prefetch overruns here: benign)
//   [8650752, 8781824)  Wf bf16 MFMA B-fragments (512 KB)
//   [8781824, 8830976)  feats fp32 [b][t][6]

__global__ void transpose_wih(const float* __restrict__ W_ih, float* __restrict__ WihT) {
    int o = blockIdx.x * blockDim.x + threadIdx.x;
    if (o >= 256 * 1024) return;
    int k = o >> 10;
    int g = o & 1023;
    WihT[o] = W_ih[g * 256 + k];
}

// Pack W_hh (fp32 [1024][256]) into bf16 MFMA B-fragments.
// flat frag f = ((k*4+n)*8+kt); lane l: g = n*256 + k*16 + (l&15), kk = kt*32 + (l>>4)*8 + j
__global__ void wf_prep(const float* __restrict__ W_hh, unsigned short* __restrict__ Wf) {
    int t = blockIdx.x * 256 + threadIdx.x;  // 0..32767
    int l = t & 63, kt = (t >> 6) & 7, n = (t >> 9) & 3, w = t >> 11;
    int g = n * 256 + w * 16 + (l & 15);
    int kk = kt * 32 + (l >> 4) * 8;
    const float* src = W_hh + g * 256 + kk;
    unsigned short* dst = Wf + (size_t)t * 8;
#pragma unroll
    for (int j = 0; j < 8; j++) dst[j] = (unsigned short)bf16_rne(src[j]);
}

// One block = 16 (b,t) rows, 1024 threads = 1 per gate. Writes Xp2 in MFMA C-layout.
__global__ __launch_bounds__(1024) void input_proj(const int* __restrict__ sentence,
                                                   const float* __restrict__ embedding,
                                                   const float* __restrict__ WihT,
                                                   const float* __restrict__ b_ih,
                                                   const float* __restrict__ b_hh,
                                                   float* __restrict__ Xp2) {
    __shared__ __align__(16) float emb[16][260];
    int tid = threadIdx.x;
    int bt0 = blockIdx.x * 16;
    {
        int r = tid >> 6, j = tid & 63;
        int row = sentence[bt0 + r];
        const float4* src = (const float4*)(embedding + (size_t)row * 256);
        float4 v = src[j];
        float* dst = &emb[r][j * 4];
        dst[0] = v.x; dst[1] = v.y; dst[2] = v.z; dst[3] = v.w;
    }
    __syncthreads();
    int g = tid;
    float bias = b_ih[g] + b_hh[g];
    float acc[16];
#pragma unroll
    for (int r = 0; r < 16; r++) acc[r] = bias;
    const float* wp = WihT + g;
    for (int k4 = 0; k4 < 64; k4++) {
        float w0 = wp[(k4 * 4 + 0) * 1024];
        float w1 = wp[(k4 * 4 + 1) * 1024];
        float w2 = wp[(k4 * 4 + 2) * 1024];
        float w3 = wp[(k4 * 4 + 3) * 1024];
#pragma unroll
        for (int r = 0; r < 16; r++) {
            float4 e = *(const float4*)&emb[r][k4 * 4];
            acc[r] += w0 * e.x + w1 * e.y + w2 * e.z + w3 * e.w;
        }
    }
    int b = bt0 >> 9, t0 = bt0 & 511;
    int q = b >> 2, j = b & 3;
    int n = g >> 8, u = g & 255, k = u >> 4, cc = u & 15;
    int lane = q * 16 + cc;
#pragma unroll
    for (int r = 0; r < 16; r++) {
        int t = t0 + r;
        Xp2[(size_t)(((t * 16 + k) * 4 + n) * 64 + lane) * 4 + j] = acc[r];
    }
}

// 16 blocks x 64 threads (ONE wave). Block k owns 16 h-units; wave computes all 4 gate
// tiles -> i/f/g/o for (batch,col) land in the SAME lane -> lane-local c/h update, zero
// barriers. Exchange: tagged {h,h,tag} u64 units at page Hg[t*2048 ..]; consumers poll
// ONE unit cheaply (s_sleep backoff), then bulk-gather once. Publishes are fire-and-forget.
__global__ __launch_bounds__(64, 1) void lstm_mfma(const unsigned short* __restrict__ Wf,
                                                   const float* Xp2,
                                                   unsigned long long* Hg) {
    __shared__ unsigned short h_tmp[16][16];
    int l = threadIdx.x;
    int k = blockIdx.x;
    int q = l >> 4, c = l & 15;

    // all 4 gate-tile B-fragments: 32 x short8 = 128 VGPR
    short8 wr[4][8];
#pragma unroll
    for (int n = 0; n < 4; n++)
#pragma unroll
        for (int kt = 0; kt < 8; kt++)
            wr[n][kt] = *(const short8*)(Wf + ((size_t)((k * 4 + n) * 8 + kt) * 64 + l) * 8);

    const char* xbase = (const char*)Xp2 + ((size_t)k * 4) * 1024 + (size_t)l * 16;
    f32x4 xv[4];
#pragma unroll
    for (int n = 0; n < 4; n++) xv[n] = *(const f32x4*)(xbase + n * 1024);

    float c_st[4] = {0.f, 0.f, 0.f, 0.f};
    // gather base: A-frag row r = l&15, k-slice pairs kt*16 + q*4 + e
    int gbase = (l & 15) * 128 + q * 4;
    // publish: lane l -> row rr = l>>2, local pairs mm, mm+1
    int rr = l >> 2, mm = (l & 3) * 2;

    for (int t = 0; t < T; t++) {
        short8 af[8];
        unsigned long long v[8][4];
        if (t > 0) {
            const unsigned long long* pb = Hg + (size_t)(t - 1) * 2048 + gbase;
            // cheap poll: 1 u64/lane until tag==t (producers store all units back-to-back)
            while (true) {
                unsigned long long p = __hip_atomic_load(pb, __ATOMIC_RELAXED,
                                                         __HIP_MEMORY_SCOPE_AGENT);
                if (__all((unsigned)(p >> 32) == (unsigned)t)) break;
                asm volatile("s_sleep 1");
            }
            // bulk gather ONCE; re-validate tags; rare retry with backoff
#pragma unroll
            for (int kt = 0; kt < 8; kt++)
#pragma unroll
                for (int e = 0; e < 4; e++)
                    v[kt][e] = __hip_atomic_load(pb + kt * 16 + e, __ATOMIC_RELAXED,
                                                 __HIP_MEMORY_SCOPE_AGENT);
            while (true) {
                bool ok = true;
#pragma unroll
                for (int kt = 0; kt < 8; kt++)
#pragma unroll
                    for (int e = 0; e < 4; e++)
                        ok = ok & ((unsigned)(v[kt][e] >> 32) == (unsigned)t);
                if (__all(ok)) break;
                asm volatile("s_sleep 2");
#pragma unroll
                for (int kt = 0; kt < 8; kt++)
#pragma unroll
                    for (int e = 0; e < 4; e++)
                        v[kt][e] = __hip_atomic_load(pb + kt * 16 + e, __ATOMIC_RELAXED,
                                                     __HIP_MEMORY_SCOPE_AGENT);
            }
#pragma unroll
            for (int kt = 0; kt < 8; kt++) {
                i32x4 pk = {(int)v[kt][0], (int)v[kt][1], (int)v[kt][2], (int)v[kt][3]};
                af[kt] = __builtin_bit_cast(short8, pk);
            }
        }

        // prefetch next step's Xp (consumed next iter; never force-drained)
        f32x4 xn[4];
        if (t + 1 < T) {
            const char* xb1 = xbase + (size_t)(t + 1) * 65536;
#pragma unroll
            for (int n = 0; n < 4; n++) xn[n] = *(const f32x4*)(xb1 + n * 1024);
        }

        f32x4 acc[4];
#pragma unroll
        for (int n = 0; n < 4; n++) acc[n] = xv[n];
        if (t > 0) {
#pragma unroll
            for (int kt = 0; kt < 8; kt++)
#pragma unroll
                for (int n = 0; n < 4; n++)
                    acc[n] = __builtin_amdgcn_mfma_f32_16x16x32_bf16(af[kt], wr[n][kt], acc[n], 0, 0, 0);
        }

        // lane-local activations: lane (q,c) owns batches q*4+j, col c
#pragma unroll
        for (int j = 0; j < 4; j++) {
            float iv = fast_sig(acc[0][j]);
            float fg = fast_sig(acc[1][j]);
            float gv = fast_tanh(acc[2][j]);
            float ov = fast_sig(acc[3][j]);
            c_st[j] = fg * c_st[j] + iv * gv;
            h_tmp[q * 4 + j][c] = (unsigned short)bf16_rne(ov * fast_tanh(c_st[j]));
        }
        asm volatile("s_waitcnt lgkmcnt(0)" ::: "memory");  // intra-wave LDS transpose

        // publish 2 tagged units/lane (fire-and-forget, no ack)
        unsigned long long tagw = (unsigned long long)(unsigned)(t + 1) << 32;
        unsigned long long* page = Hg + (size_t)t * 2048;
#pragma unroll
        for (int s = 0; s < 2; s++) {
            int m = mm + s;
            unsigned lo = *(const unsigned*)&h_tmp[rr][2 * m];
            __hip_atomic_store(page + rr * 128 + k * 8 + m, lo | tagw,
                               __ATOMIC_RELAXED, __HIP_MEMORY_SCOPE_AGENT);
        }
#pragma unroll
        for (int n = 0; n < 4; n++) xv[n] = xn[n];
    }
}

// feats[b][t][tag] = h(b,t) . W_out[tag] + b_out[tag].  2048 blocks x 256, wave = one (b,t).
__global__ __launch_bounds__(256) void feats_k(const unsigned long long* __restrict__ Hg,
                                               const float* __restrict__ W_out,
                                               const float* __restrict__ b_out,
                                               float* __restrict__ feats) {
    int wid = blockIdx.x * 4 + (threadIdx.x >> 6);
    int l = threadIdx.x & 63;
    int b = wid >> 9, t = wid & 511;
    // lane l covers u = l*4 + {0..3} -> units b*128 + 2l, 2l+1 -> one 16B load
    const uint4* src = (const uint4*)(Hg + (size_t)t * 2048 + b * 128) + l;
    uint4 v = *src;
    float h0 = __builtin_bit_cast(float, (v.x & 0xffffu) << 16);
    float h1 = __builtin_bit_cast(float, v.x & 0xffff0000u);
    float h2 = __builtin_bit_cast(float, (v.z & 0xffffu) << 16);
    float h3 = __builtin_bit_cast(float, v.z & 0xffff0000u);
    int ub = l * 4;
#pragma unroll
    for (int tag = 0; tag < 6; tag++) {
        float4 w = *(const float4*)(W_out + tag * 256 + ub);
        float p = h0 * w.x + h1 * w.y + h2 * w.z + h3 * w.w;
#pragma unroll
        for (int off = 32; off; off >>= 1) p += __shfl_down(p, off);
        if (l == 0) feats[((size_t)b * 512 + t) * 6 + tag] = p + b_out[tag];
    }
}

// 16 blocks x 64 threads. Lane nx owns next-tag nx; fv broadcast via shfl each step.
__global__ __launch_bounds__(64) void crf_scan(const float* __restrict__ feats,
                                               const float* __restrict__ trans,
                                               float* __restrict__ out) {
    __shared__ float fl[T * 6];
    __shared__ unsigned char bp[T * 8];
    int b = blockIdx.x, tid = threadIdx.x;
    const float4* src = (const float4*)(feats + (size_t)b * 3072);
#pragma unroll
    for (int i = 0; i < 12; i++) ((float4*)fl)[tid + i * 64] = src[tid + i * 64];
    int nx = (tid < 6) ? tid : 0;
    float tr0 = trans[nx * 6 + 0], tr1 = trans[nx * 6 + 1], tr2 = trans[nx * 6 + 2],
          tr3 = trans[nx * 6 + 3], tr4 = trans[nx * 6 + 4], tr5 = trans[nx * 6 + 5];
    float fv0 = NEGV, fv1 = NEGV, fv2 = NEGV, fv3 = NEGV, fv4 = 0.f, fv5 = NEGV;  // START=4
    __syncthreads();
    for (int t = 0; t < T; t++) {
        float best = fv0 + tr0; int arg = 0; float s;
        s = fv1 + tr1; if (s > best) { best = s; arg = 1; }
        s = fv2 + tr2; if (s > best) { best = s; arg = 2; }
        s = fv3 + tr3; if (s > best) { best = s; arg = 3; }
        s = fv4 + tr4; if (s > best) { best = s; arg = 4; }
        s = fv5 + tr5; if (s > best) { best = s; arg = 5; }  // strict >: first-max
        float nf = best + fl[t * 6 + nx];
        if (tid < 6) bp[t * 8 + tid] = (unsigned char)arg;
        fv0 = __shfl(nf, 0); fv1 = __shfl(nf, 1); fv2 = __shfl(nf, 2);
        fv3 = __shfl(nf, 3); fv4 = __shfl(nf, 4); fv5 = __shfl(nf, 5);
    }
    __syncthreads();
    if (tid == 0) {
        float best = fv0 + trans[STOP * 6 + 0]; int arg = 0; float s;
        s = fv1 + trans[STOP * 6 + 1]; if (s > best) { best = s; arg = 1; }
        s = fv2 + trans[STOP * 6 + 2]; if (s > best) { best = s; arg = 2; }
        s = fv3 + trans[STOP * 6 + 3]; if (s > best) { best = s; arg = 3; }
        s = fv4 + trans[STOP * 6 + 4]; if (s > best) { best = s; arg = 4; }
        s = fv5 + trans[STOP * 6 + 5]; if (s > best) { best = s; arg = 5; }
        out[b] = best;
        int tag = arg;
        float* paths = out + 16 + (size_t)b * 512;
        for (int t = T - 1; t >= 0; t--) {
            paths[t] = (float)tag;
            tag = bp[t * 8 + tag];
        }
    }
}

extern "C" void kernel_launch(void* const* d_in, const int* in_sizes, int n_in,
                              void* d_out, int out_size, void* d_ws, size_t ws_size,
                              hipStream_t stream) {
    const int* sentence = (const int*)d_in[0];
    const float* embedding = (const float*)d_in[1];
    const float* W_ih = (const float*)d_in[2];
    const float* W_hh = (const float*)d_in[3];
    const float* b_ih = (const float*)d_in[4];
    const float* b_hh = (const float*)d_in[5];
    const float* W_out = (const float*)d_in[6];
    const float* b_out = (const float*)d_in[7];
    const float* trans = (const float*)d_in[8];
    float* out = (float*)d_out;
    float* ws = (float*)d_ws;

    float* Xp2 = ws;
    unsigned long long* Hg = (unsigned long long*)ws;  // aliases Xp2 head (consumed region)
    float* WihT = ws + 8388608;
    unsigned short* Wf = (unsigned short*)(ws + 8650752);
    float* feats = ws + 8781824;

    hipLaunchKernelGGL(transpose_wih, dim3(1024), dim3(256), 0, stream, W_ih, WihT);
    hipLaunchKernelGGL(input_proj, dim3(BATCH * T / 16), dim3(1024), 0, stream,
                       sentence, embedding, WihT, b_ih, b_hh, Xp2);
    hipLaunchKernelGGL(wf_prep, dim3(128), dim3(256), 0, stream, W_hh, Wf);
    hipLaunchKernelGGL(lstm_mfma, dim3(NBLK), dim3(64), 0, stream, Wf, Xp2, Hg);
    hipLaunchKernelGGL(feats_k, dim3(2048), dim3(256), 0, stream, Hg, W_out, b_out, feats);
    hipLaunchKernelGGL(crf_scan, dim3(BATCH), dim3(64), 0, stream, feats, trans, out);
}